// Round 22
// baseline (88.718 us; speedup 1.0000x reference)
//
#include <hip/hip_runtime.h>
#include <hip/hip_bf16.h>

#define SEQ 2048

typedef short s4v __attribute__((ext_vector_type(4)));
typedef float f32x4 __attribute__((ext_vector_type(4)));

using bf16 = __hip_bfloat16;
using ull = unsigned long long;

// Raw hardware exp2 (v_exp_f32). Safe with NO inline asm in this TU (r13 proved;
// r8/r9 NaNs were hand-written asm cvt_pk reading TRANS results unguarded).
#if __has_builtin(__builtin_amdgcn_exp2f)
#define EXP2(x) __builtin_amdgcn_exp2f(x)
#else
#define EXP2(x) exp2f(x)
#endif

// Wave priority hint around MFMA/exp compute clusters (T5, m191: +4-7% on
// attention with independent de-phased waves; our main loop is barrier-free).
#if __has_builtin(__builtin_amdgcn_s_setprio)
#define PRIO(n) __builtin_amdgcn_s_setprio(n)
#else
#define PRIO(n)
#endif

__device__ __forceinline__ float wred_sum(float v){
#pragma unroll
  for (int i = 1; i < 64; i <<= 1) v += __shfl_xor(v, i, 64);
  return v;
}

__device__ __forceinline__ float wred_max(float v){
#pragma unroll
  for (int i = 1; i < 64; i <<= 1) v = fmaxf(v, __shfl_xor(v, i, 64));
  return v;
}

// Compiler-generated f32->bf16 RNE (no inline asm -- r8/r9/r11 lesson).
__device__ __forceinline__ short bfs(float f){
  bf16 h = __float2bfloat16(f);
  short s;
  __builtin_memcpy(&s, &h, 2);
  return s;
}

// Packed 2xf32 -> 2xbf16 RNE through the supported API (compiler emits cvt_pk).
__device__ __forceinline__ unsigned bfs2(float a, float b){
  float2 t; t.x = a; t.y = b;
  __hip_bfloat162 h = __float22bfloat162_rn(t);
  unsigned u;
  __builtin_memcpy(&u, &h, 4);
  return u;
}

// Detect whether a "float" input buffer is really f32 (1) or bf16 (0).
__device__ __forceinline__ int detect_f32(const void* xraw){
  const unsigned short* p = (const unsigned short*)xraw;
  const int lane = threadIdx.x & 63;
  float mx = 0.f;
#pragma unroll
  for (int i = 0; i < 2; ++i){
    unsigned u = ((unsigned)p[lane * 2 + i]) << 16;
    float f = fabsf(__uint_as_float(u));
    if (!(f < 1e30f)) f = 1e30f;       // NaN/Inf -> large
    mx = fmaxf(mx, f);
  }
  mx = wred_max(mx);
  return mx > 1e3f ? 1 : 0;
}

template<int F32>
__device__ __forceinline__ float ldf(const void* p, int i){
  if constexpr (F32) return ((const float*)p)[i];
  else return __bfloat162float(((const bf16*)p)[i]);
}

// log2(e)/sqrt(dk) folded into Q at projection time
#define QSCALE 0.5101129340352065f

// ---------------- Kernel P: mask-pack + LN1/QKV + weight-transpose + ones ------
template<int F32>
__device__ __forceinline__ void ln_qkv_body(
    const void* x,
    const void* Wq, const void* bq,
    const void* Wk, const void* bk,
    const void* Wv, const void* bv,
    const void* ln1w, const void* ln1b,
    float* x1f, bf16* Qp, bf16* Kp, bf16* Vti, float (*xs)[64])
{
  const int w = threadIdx.x >> 6, lane = threadIdx.x & 63;
  const int row = (blockIdx.x - 2048) * 4 + w;        // 0..8191 (= b*2048+s)
  float xv = ldf<F32>(x, row * 64 + lane);
  float mu = wred_sum(xv) * 0.015625f;
  float dv = xv - mu;
  float var = wred_sum(dv * dv) * 0.015625f;
  float x1 = dv * rsqrtf(var + 1e-5f) * ldf<F32>(ln1w, lane) + ldf<F32>(ln1b, lane);
  x1f[(size_t)row * 64 + lane] = x1;
  xs[w][lane] = x1;
  __syncthreads();
  float q = ldf<F32>(bq, lane);
  float k = ldf<F32>(bk, lane);
  float v = ldf<F32>(bv, lane);
#pragma unroll 16
  for (int d = 0; d < 64; ++d){
    float xd = xs[w][d];                              // LDS broadcast
    q += xd * ldf<F32>(Wq, d * 64 + lane);            // contiguous per d
    k += xd * ldf<F32>(Wk, d * 64 + lane);
    v += xd * ldf<F32>(Wv, d * 64 + lane);
  }
  // packed per-head layout [bh][s][8] for Q,K
  const int bq_ = row >> 11, sq = row & 2047;
  const int hh = lane >> 3, dd = lane & 7;
  const int bh = bq_ * 8 + hh;
  const size_t pidx = ((size_t)bh * SEQ + sq) * 8 + dd;
  Qp[pidx] = __float2bfloat16(q * QSCALE);            // pre-scaled
  Kp[pidx] = __float2bfloat16(k);
  // V scattered directly into interleaved Vti[bh][tt][dd][j] (2B store/lane)
  const int tt = sq >> 4, j = sq & 15;
  Vti[(((size_t)(bh * 128 + tt)) * 9 + dd) * 16 + j] = __float2bfloat16(v);
}

template<int F32>
__device__ __forceinline__ void wt_body(
    const void* Wo, const void* W1, const void* W2,
    bf16* WoT, bf16* W1T, bf16* W2T)
{
  const int idx = (blockIdx.x - 4096) * 256 + threadIdx.x;
  if (idx < 4096){
    const int c = idx >> 6, d = idx & 63;
    WoT[idx] = __float2bfloat16(ldf<F32>(Wo, d * 64 + c));
  } else if (idx < 20480){
    const int e = idx - 4096;
    const int f = e >> 6, d = e & 63;
    W1T[e] = __float2bfloat16(ldf<F32>(W1, d * 256 + f));
  } else {
    const int e = idx - 20480;
    const int c = e >> 8, f = e & 255;
    W2T[e] = __float2bfloat16(ldf<F32>(W2, f * 64 + c));
  }
}

__global__ __launch_bounds__(256) void k_prep(
    const int* __restrict__ mask, ull* __restrict__ pm,
    const void* x, const void* Wq, const void* bq, const void* Wk, const void* bk,
    const void* Wv, const void* bv, const void* ln1w, const void* ln1b,
    float* x1f, bf16* Qp, bf16* Kp, bf16* Vti,
    const void* Wo, const void* W1, const void* W2,
    bf16* WoT, bf16* W1T, bf16* W2T)
{
  __shared__ float xs[4][64];
  const int w = threadIdx.x >> 6, lane = threadIdx.x & 63;
  if (blockIdx.x < 2048){
    const int row = blockIdx.x * 4 + w;               // 0..8191 (= b*2048+q)
    const int b = row >> 11, q = row & 2047;
    const int* rp = mask + (size_t)row * SEQ;
    ull* op = pm + ((size_t)(b * 128 + (q >> 4))) * 512 + (q & 15) * 2;
#pragma unroll
    for (int it = 0; it < 8; ++it){
      const int c0 = it * 256 + lane;
      ull m0 = __ballot(rp[c0] == 1);
      ull m1 = __ballot(rp[c0 + 64] == 1);
      ull m2 = __ballot(rp[c0 + 128] == 1);
      ull m3 = __ballot(rp[c0 + 192] == 1);
      if (lane == 0){
#pragma unroll
        for (int j = 0; j < 4; ++j){
          const int wi = it * 4 + j;
          const ull mv = (j == 0) ? m0 : (j == 1) ? m1 : (j == 2) ? m2 : m3;
          op[(wi >> 1) * 32 + (wi & 1)] = mv;
        }
      }
    }
    return;
  }
  if (blockIdx.x >= 4240){
    // ones-rows of Vti: [bh][tt][8][j] = 1.0  (65536 bf16)
    const int idx = (blockIdx.x - 4240) * 256 + threadIdx.x;
    const int bh = idx >> 11;
    const int rem = idx & 2047;
    const int tt = rem >> 4, j = rem & 15;
    Vti[(((size_t)(bh * 128 + tt)) * 9 + 8) * 16 + j] = __float2bfloat16(1.0f);
    return;
  }
  if (blockIdx.x >= 4096){
    if (detect_f32(x)) wt_body<1>(Wo, W1, W2, WoT, W1T, W2T);
    else               wt_body<0>(Wo, W1, W2, WoT, W1T, W2T);
    return;
  }
  if (detect_f32(x))
    ln_qkv_body<1>(x, Wq, bq, Wk, bk, Wv, bv, ln1w, ln1b, x1f, Qp, Kp, Vti, xs);
  else
    ln_qkv_body<0>(x, Wq, bq, Wk, bk, Wv, bv, ln1w, ln1b, x1f, Qp, Kp, Vti, xs);
}

// ---------------- Kernel B: flash attention, 2 q-tiles/wave + K/4-split --------
// 256 thr = 4 waves = 1 head x 4 K-quarters; 32 queries/block. Fixed-ref
// softmax (raw v_exp); denominator via V ones-row; quarters merged additively
// through LDS. setprio(1) around each compute cluster (T5). No sched_barrier
// (r20: spill) and no inline asm (r8/r9/r11).
#define LOADT(PB, T) do {                                                          \
    const int tt_ = (T);                                                           \
    _Pragma("unroll")                                                              \
    for (int i_ = 0; i_ < 8; ++i_){                                                \
      kf[PB][i_] = *reinterpret_cast<const s4v*>(kb8 + (size_t)(tt_ * 128 + i_ * 16) * 8); \
      vf[PB][i_] = *reinterpret_cast<const s4v*>(vb8 + (size_t)(tt_ * 8 + i_) * 144);      \
    }                                                                              \
    mwvA[PB] = pbA[tt_ * 16];                                                      \
    mwvB[PB] = pbB[tt_ * 16];                                                      \
  } while (0)

#define QTILE(PB, C, WLO, WHI, QF, ACCA, ACCB) do {                                \
    f32x4 st_[4];                                                                  \
    PRIO(1);                                                                       \
    _Pragma("unroll")                                                              \
    for (int i_ = 0; i_ < 4; ++i_)                                                 \
      st_[i_] = __builtin_amdgcn_mfma_f32_16x16x16bf16_1k(kf[PB][(C) * 4 + i_], QF, zf, 0, 0, 0); \
    _Pragma("unroll")                                                              \
    for (int i_ = 0; i_ < 4; ++i_){                                                \
      const unsigned w32_ = (i_ < 2) ? (WLO) : (WHI);                              \
      const unsigned b4_ = (w32_ >> (16 * (i_ & 1) + sh4)) & 0xFu;                 \
      float p0_ = (b4_ & 1u) ? 0.f : EXP2(st_[i_][0]);                             \
      float p1_ = (b4_ & 2u) ? 0.f : EXP2(st_[i_][1]);                             \
      float p2_ = (b4_ & 4u) ? 0.f : EXP2(st_[i_][2]);                             \
      float p3_ = (b4_ & 8u) ? 0.f : EXP2(st_[i_][3]);                             \
      union { unsigned u[2]; s4v s; } pu_;                                         \
      pu_.u[0] = bfs2(p0_, p1_);                                                   \
      pu_.u[1] = bfs2(p2_, p3_);                                                   \
      if (i_ & 1) ACCB = __builtin_amdgcn_mfma_f32_16x16x16bf16_1k(vf[PB][(C) * 4 + i_], pu_.s, ACCB, 0, 0, 0); \
      else        ACCA = __builtin_amdgcn_mfma_f32_16x16x16bf16_1k(vf[PB][(C) * 4 + i_], pu_.s, ACCA, 0, 0, 0); \
    }                                                                              \
    PRIO(0);                                                                       \
  } while (0)

#define COMPT(PB) do {                                                             \
    QTILE(PB, 0, mwvA[PB].x, mwvA[PB].y, qfA, accA0, accB0);                       \
    QTILE(PB, 0, mwvB[PB].x, mwvB[PB].y, qfB, accA1, accB1);                       \
    QTILE(PB, 1, mwvA[PB].z, mwvA[PB].w, qfA, accA0, accB0);                       \
    QTILE(PB, 1, mwvB[PB].z, mwvB[PB].w, qfB, accA1, accB1);                       \
  } while (0)

__global__ __launch_bounds__(256, 4) void k_attn(
    const bf16* __restrict__ Qp, const bf16* __restrict__ Kp,
    const bf16* __restrict__ Vti, const uint4* __restrict__ pmi,
    bf16* __restrict__ ctxb)
{
  const int blk = blockIdx.x;                 // 2048 = b(4) x qt(64) x h(8)
  const int h  = blk & 7;
  const int qt = (blk >> 3) & 63;
  const int b  = blk >> 9;
  const int kq = threadIdx.x >> 6;            // K-quarter 0..3
  const int bh = b * 8 + h;
  const int q0 = qt * 32;
  const int lane = threadIdx.x & 63;
  const int g = lane >> 4, qi = lane & 15;
  const int sh4 = 4 * g;
  const int tbase = kq * 4;                   // 4 tiles of 128 keys per wave

  __shared__ float mlds[3][2][16][17];

  s4v qfA = {0, 0, 0, 0}, qfB = {0, 0, 0, 0};
  if (g < 2){
    qfA = *reinterpret_cast<const s4v*>(Qp + ((size_t)(bh * SEQ + q0 + qi)) * 8 + sh4);
    qfB = *reinterpret_cast<const s4v*>(Qp + ((size_t)(bh * SEQ + q0 + 16 + qi)) * 8 + sh4);
  }

  const bf16*  kb8 = Kp + ((size_t)bh * SEQ + qi) * 8 + sh4;
  const bf16*  vb8 = Vti + (size_t)bh * 128 * 144 + qi * 16 + sh4;
  const uint4* pbA = pmi + (size_t)(b * 128 + 2 * qt) * 256 + qi;
  const uint4* pbB = pbA + 256;

  f32x4 accA0 = {0.f, 0.f, 0.f, 0.f}, accB0 = {0.f, 0.f, 0.f, 0.f};
  f32x4 accA1 = {0.f, 0.f, 0.f, 0.f}, accB1 = {0.f, 0.f, 0.f, 0.f};
  const f32x4 zf = {0.f, 0.f, 0.f, 0.f};

  s4v kf[2][8], vf[2][8];
  uint4 mwvA[2], mwvB[2];

  LOADT(0, tbase);
#pragma unroll
  for (int it2 = 0; it2 < 2; ++it2){
    LOADT(1, tbase + ((2 * it2 + 1) & 3));
    COMPT(0);
    LOADT(0, tbase + ((2 * it2 + 2) & 3));
    COMPT(1);
  }

  f32x4 acc0, acc1;
#pragma unroll
  for (int r = 0; r < 4; ++r){
    acc0[r] = accA0[r] + accB0[r];
    acc1[r] = accA1[r] + accB1[r];
  }

  // merge the four K-quarters (additive: fixed-ref softmax, unnormalized)
  if (kq > 0){
#pragma unroll
    for (int r = 0; r < 4; ++r){
      mlds[kq - 1][0][4 * g + r][qi] = acc0[r];
      mlds[kq - 1][1][4 * g + r][qi] = acc1[r];
    }
  }
  __syncthreads();
  if (kq == 0){
#pragma unroll
    for (int j = 0; j < 3; ++j)
#pragma unroll
      for (int r = 0; r < 4; ++r){
        acc0[r] += mlds[j][0][4 * g + r][qi];
        acc1[r] += mlds[j][1][4 * g + r][qi];
      }
    // denominator lives in D row 8 (lane 32+qi, reg 0), col = query
    const float s0 = __shfl(acc0[0], 32 + qi, 64);
    const float s1 = __shfl(acc1[0], 32 + qi, 64);
    if (g < 2){
      const float i0 = 1.f / s0, i1 = 1.f / s1;
      s4v oA, oB;
#pragma unroll
      for (int r = 0; r < 4; ++r){ oA[r] = bfs(acc0[r] * i0); oB[r] = bfs(acc1[r] * i1); }
      *reinterpret_cast<s4v*>(ctxb + ((size_t)(bh * SEQ + q0 + qi)) * 8 + sh4) = oA;
      *reinterpret_cast<s4v*>(ctxb + ((size_t)(bh * SEQ + q0 + 16 + qi)) * 8 + sh4) = oB;
    }
  }
}

// ---------------- Kernel C: MFMA FFN, u-split across 4 waves -------------------
template<int F32>
__device__ __forceinline__ void ffn_mfma_body(
    const bf16* __restrict__ ctxb, const float* __restrict__ x1f,
    const bf16* __restrict__ WoT, const bf16* __restrict__ W1T, const bf16* __restrict__ W2T,
    const void* bo, const void* b1, const void* b2,
    const void* ln2w, const void* ln2b, void* out, float (*mlds)[16][64])
{
  const int lane = threadIdx.x & 63;
  const int uq = threadIdx.x >> 6;    // u-quarter 0..3
  const int row0 = blockIdx.x * 16;
  const int xr = lane & 15;           // x-row within tile == D col
  const int ko = (lane >> 4) * 4;     // k/col offset of this lane's quad
  const f32x4 zf = {0.f, 0.f, 0.f, 0.f};

  // ctx B-frags (K-steps kk=0..3):  B[k=16kk+ko+j][n=xr]
  s4v cb[4];
#pragma unroll
  for (int kk = 0; kk < 4; ++kk)
    cb[kk] = *reinterpret_cast<const s4v*>(ctxb + (size_t)(row0 + xr) * 64 + kk * 16 + ko);

  // GEMM1: proj^T tiles; x2 = 2*x1 + proj + bo   (lane holds x2[xr][16t+ko+r])
  float x2v[4][4];
#pragma unroll
  for (int t = 0; t < 4; ++t){
    f32x4 acc = zf;
#pragma unroll
    for (int kk = 0; kk < 4; ++kk){
      s4v a = *reinterpret_cast<const s4v*>(WoT + (size_t)(t * 16 + xr) * 64 + kk * 16 + ko);
      acc = __builtin_amdgcn_mfma_f32_16x16x16bf16_1k(a, cb[kk], acc, 0, 0, 0);
    }
    float4 x1q = *reinterpret_cast<const float4*>(x1f + (size_t)(row0 + xr) * 64 + t * 16 + ko);
#pragma unroll
    for (int r = 0; r < 4; ++r)
      x2v[t][r] = 2.f * (&x1q.x)[r] + acc[r] + ldf<F32>(bo, t * 16 + ko + r);
  }

  // LN2: all 16 values belong to row xr; row spans lanes {xr, xr+16, xr+32, xr+48}
  float s = 0.f;
#pragma unroll
  for (int t = 0; t < 4; ++t)
#pragma unroll
    for (int r = 0; r < 4; ++r) s += x2v[t][r];
  s += __shfl_xor(s, 16, 64);
  s += __shfl_xor(s, 32, 64);
  const float mu = s * 0.015625f;
  float vs = 0.f;
#pragma unroll
  for (int t = 0; t < 4; ++t)
#pragma unroll
    for (int r = 0; r < 4; ++r){ float d = x2v[t][r] - mu; vs += d * d; }
  vs += __shfl_xor(vs, 16, 64);
  vs += __shfl_xor(vs, 32, 64);
  const float rs = rsqrtf(vs * 0.015625f + 1e-5f);

  // x3 frags: B-operand for GEMM2, K-step t  (j == r)
  s4v xb[4];
#pragma unroll
  for (int t = 0; t < 4; ++t)
#pragma unroll
    for (int r = 0; r < 4; ++r)
      xb[t][r] = bfs((x2v[t][r] - mu) * rs * ldf<F32>(ln2w, t * 16 + ko + r)
                     + ldf<F32>(ln2b, t * 16 + ko + r));

  // GEMM2 + b1 + exact gelu for this wave's 4 u-tiles
  s4v gb[4];
#pragma unroll
  for (int uu = 0; uu < 4; ++uu){
    const int u = uq * 4 + uu;
    f32x4 acc = zf;
#pragma unroll
    for (int t = 0; t < 4; ++t){
      s4v a = *reinterpret_cast<const s4v*>(W1T + (size_t)(u * 16 + xr) * 64 + t * 16 + ko);
      acc = __builtin_amdgcn_mfma_f32_16x16x16bf16_1k(a, xb[t], acc, 0, 0, 0);
    }
#pragma unroll
    for (int r = 0; r < 4; ++r){
      float h1 = acc[r] + ldf<F32>(b1, u * 16 + ko + r);
      gb[uu][r] = bfs(0.5f * h1 * (1.f + erff(h1 * 0.70710678f)));
    }
  }

  // partial GEMM3 over this wave's u-tiles
  f32x4 oacc[4];
#pragma unroll
  for (int t = 0; t < 4; ++t){
    f32x4 acc = zf;
#pragma unroll
    for (int uu = 0; uu < 4; ++uu){
      const int u = uq * 4 + uu;
      s4v a = *reinterpret_cast<const s4v*>(W2T + (size_t)(t * 16 + xr) * 256 + u * 16 + ko);
      acc = __builtin_amdgcn_mfma_f32_16x16x16bf16_1k(a, gb[uu], acc, 0, 0, 0);
    }
    oacc[t] = acc;
  }

  // merge partials (additive) through LDS; wave 0 finalizes
  if (uq > 0){
#pragma unroll
    for (int t = 0; t < 4; ++t)
#pragma unroll
      for (int r = 0; r < 4; ++r)
        mlds[uq - 1][xr][t * 16 + ko + r] = oacc[t][r];
  }
  __syncthreads();
  if (uq == 0){
#pragma unroll
    for (int t = 0; t < 4; ++t){
#pragma unroll
      for (int j = 0; j < 3; ++j)
#pragma unroll
        for (int r = 0; r < 4; ++r)
          oacc[t][r] += mlds[j][xr][t * 16 + ko + r];
      const size_t oidx = (size_t)(row0 + xr) * 64 + t * 16 + ko;
      if constexpr (F32){
        float4 o;
#pragma unroll
        for (int r = 0; r < 4; ++r)
          (&o.x)[r] = x2v[t][r] + oacc[t][r] + ldf<F32>(b2, t * 16 + ko + r);
        *reinterpret_cast<float4*>((float*)out + oidx) = o;
      } else {
        s4v o;
#pragma unroll
        for (int r = 0; r < 4; ++r)
          o[r] = bfs(x2v[t][r] + oacc[t][r] + ldf<F32>(b2, t * 16 + ko + r));
        *reinterpret_cast<s4v*>((bf16*)out + oidx) = o;
      }
    }
  }
}

__global__ __launch_bounds__(256) void k_ffn(
    const void* xprobe,
    const bf16* __restrict__ ctxb, const float* __restrict__ x1f,
    const bf16* __restrict__ WoT, const bf16* __restrict__ W1T, const bf16* __restrict__ W2T,
    const void* bo, const void* b1, const void* b2,
    const void* ln2w, const void* ln2b, void* out)
{
  __shared__ float mlds[3][16][64];
  if (detect_f32(xprobe))
    ffn_mfma_body<1>(ctxb, x1f, WoT, W1T, W2T, bo, b1, b2, ln2w, ln2b, out, mlds);
  else
    ffn_mfma_body<0>(ctxb, x1f, WoT, W1T, W2T, bo, b1, b2, ln2w, ln2b, out, mlds);
}

extern "C" void kernel_launch(void* const* d_in, const int* in_sizes, int n_in,
                              void* d_out, int out_size, void* d_ws, size_t ws_size,
                              hipStream_t stream)
{
  (void)in_sizes; (void)n_in; (void)out_size; (void)ws_size;
  const void* x    = d_in[0];
  const int*  mask = (const int*)d_in[1];
  const void* Wq = d_in[2];
  const void* bq = d_in[3];
  const void* Wk = d_in[4];
  const void* bk = d_in[5];
  const void* Wv = d_in[6];
  const void* bv = d_in[7];
  const void* Wo = d_in[8];
  const void* bo = d_in[9];
  const void* W1 = d_in[10];
  const void* b1 = d_in[11];
  const void* W2 = d_in[12];
  const void* b2 = d_in[13];
  const void* ln1w = d_in[14];
  const void* ln1b = d_in[15];
  const void* ln2w = d_in[16];
  const void* ln2b = d_in[17];

  char* ws = (char*)d_ws;
  float* x1f = (float*)(ws + 0);               // 2 MB     [B][S][64] f32
  bf16*  Qp  = (bf16*)(ws + (2u << 20));       // 1 MB     [bh][s][8] bf16 (pre-scaled)
  bf16*  Kp  = (bf16*)(ws + (3u << 20));       // 1 MB     [bh][s][8]
  bf16*  Vti = (bf16*)(ws + (5u << 20));       // 1.125 MB [bh][tt][9][16], row8=ones
  bf16*  ctxb= (bf16*)(ws + (25u << 18));      // 1 MB     [B][H][S][8] bf16 (@6.25MB)
  bf16*  WoT = (bf16*)(ws + (29u << 18));      // 8 KB     [64][64]  (@7.25MB)
  bf16*  W1T = (bf16*)(ws + (29u << 18) + 8192);   // 32 KB [256][64]
  bf16*  W2T = (bf16*)(ws + (29u << 18) + 40960);  // 32 KB [64][256]
  ull*   pm  = (ull*)(ws + (33u << 18));       // 2 MB     packed mask (@8.25MB)

  k_prep<<<4496, 256, 0, stream>>>(mask, pm, x, Wq, bq, Wk, bk, Wv, bv, ln1w, ln1b,
                                   x1f, Qp, Kp, Vti, Wo, W1, W2, WoT, W1T, W2T);
  k_attn<<<2048, 256, 0, stream>>>(Qp, Kp, Vti, (const uint4*)pm, ctxb);
  k_ffn<<<512, 256, 0, stream>>>(x, ctxb, x1f, WoT, W1T, W2T, bo, b1, b2, ln2w, ln2b, d_out);
}

// Round 23
// 81.056 us; speedup vs baseline: 1.0945x; 1.0945x over previous
//
#include <hip/hip_runtime.h>
#include <hip/hip_bf16.h>

#define SEQ 2048

typedef short s4v __attribute__((ext_vector_type(4)));
typedef float f32x4 __attribute__((ext_vector_type(4)));

using bf16 = __hip_bfloat16;
using ull = unsigned long long;

// Raw hardware exp2 (v_exp_f32). Safe with NO inline asm in this TU (r13 proved;
// r8/r9 NaNs were hand-written asm cvt_pk reading TRANS results unguarded).
#if __has_builtin(__builtin_amdgcn_exp2f)
#define EXP2(x) __builtin_amdgcn_exp2f(x)
#else
#define EXP2(x) exp2f(x)
#endif

__device__ __forceinline__ float wred_sum(float v){
#pragma unroll
  for (int i = 1; i < 64; i <<= 1) v += __shfl_xor(v, i, 64);
  return v;
}

__device__ __forceinline__ float wred_max(float v){
#pragma unroll
  for (int i = 1; i < 64; i <<= 1) v = fmaxf(v, __shfl_xor(v, i, 64));
  return v;
}

// Compiler-generated f32->bf16 RNE (no inline asm -- r8/r9/r11 lesson).
__device__ __forceinline__ short bfs(float f){
  bf16 h = __float2bfloat16(f);
  short s;
  __builtin_memcpy(&s, &h, 2);
  return s;
}

// Packed 2xf32 -> 2xbf16 RNE through the supported API (compiler emits cvt_pk).
__device__ __forceinline__ unsigned bfs2(float a, float b){
  float2 t; t.x = a; t.y = b;
  __hip_bfloat162 h = __float22bfloat162_rn(t);
  unsigned u;
  __builtin_memcpy(&u, &h, 4);
  return u;
}

// Detect whether a "float" input buffer is really f32 (1) or bf16 (0).
__device__ __forceinline__ int detect_f32(const void* xraw){
  const unsigned short* p = (const unsigned short*)xraw;
  const int lane = threadIdx.x & 63;
  float mx = 0.f;
#pragma unroll
  for (int i = 0; i < 2; ++i){
    unsigned u = ((unsigned)p[lane * 2 + i]) << 16;
    float f = fabsf(__uint_as_float(u));
    if (!(f < 1e30f)) f = 1e30f;       // NaN/Inf -> large
    mx = fmaxf(mx, f);
  }
  mx = wred_max(mx);
  return mx > 1e3f ? 1 : 0;
}

template<int F32>
__device__ __forceinline__ float ldf(const void* p, int i){
  if constexpr (F32) return ((const float*)p)[i];
  else return __bfloat162float(((const bf16*)p)[i]);
}

// log2(e)/sqrt(dk) folded into Q at projection time
#define QSCALE 0.5101129340352065f

// ---------------- Kernel P: mask-pack + LN1/QKV + weight-transpose + ones ------
template<int F32>
__device__ __forceinline__ void ln_qkv_body(
    const void* x,
    const void* Wq, const void* bq,
    const void* Wk, const void* bk,
    const void* Wv, const void* bv,
    const void* ln1w, const void* ln1b,
    float* x1f, bf16* Qp, bf16* Kp, bf16* Vti, float (*xs)[64])
{
  const int w = threadIdx.x >> 6, lane = threadIdx.x & 63;
  const int row = (blockIdx.x - 2048) * 4 + w;        // 0..8191 (= b*2048+s)
  float xv = ldf<F32>(x, row * 64 + lane);
  float mu = wred_sum(xv) * 0.015625f;
  float dv = xv - mu;
  float var = wred_sum(dv * dv) * 0.015625f;
  float x1 = dv * rsqrtf(var + 1e-5f) * ldf<F32>(ln1w, lane) + ldf<F32>(ln1b, lane);
  x1f[(size_t)row * 64 + lane] = x1;
  xs[w][lane] = x1;
  __syncthreads();
  float q = ldf<F32>(bq, lane);
  float k = ldf<F32>(bk, lane);
  float v = ldf<F32>(bv, lane);
#pragma unroll 16
  for (int d = 0; d < 64; ++d){
    float xd = xs[w][d];                              // LDS broadcast
    q += xd * ldf<F32>(Wq, d * 64 + lane);            // contiguous per d
    k += xd * ldf<F32>(Wk, d * 64 + lane);
    v += xd * ldf<F32>(Wv, d * 64 + lane);
  }
  // packed per-head layout [bh][s][8] for Q,K
  const int bq_ = row >> 11, sq = row & 2047;
  const int hh = lane >> 3, dd = lane & 7;
  const int bh = bq_ * 8 + hh;
  const size_t pidx = ((size_t)bh * SEQ + sq) * 8 + dd;
  Qp[pidx] = __float2bfloat16(q * QSCALE);            // pre-scaled
  Kp[pidx] = __float2bfloat16(k);
  // V scattered directly into interleaved Vti[bh][tt][dd][j] (2B store/lane)
  const int tt = sq >> 4, j = sq & 15;
  Vti[(((size_t)(bh * 128 + tt)) * 9 + dd) * 16 + j] = __float2bfloat16(v);
}

template<int F32>
__device__ __forceinline__ void wt_body(
    const void* Wo, const void* W1, const void* W2,
    bf16* WoT, bf16* W1T, bf16* W2T)
{
  const int idx = (blockIdx.x - 4096) * 256 + threadIdx.x;
  if (idx < 4096){
    const int c = idx >> 6, d = idx & 63;
    WoT[idx] = __float2bfloat16(ldf<F32>(Wo, d * 64 + c));
  } else if (idx < 20480){
    const int e = idx - 4096;
    const int f = e >> 6, d = e & 63;
    W1T[e] = __float2bfloat16(ldf<F32>(W1, d * 256 + f));
  } else {
    const int e = idx - 20480;
    const int c = e >> 8, f = e & 255;
    W2T[e] = __float2bfloat16(ldf<F32>(W2, f * 64 + c));
  }
}

__global__ __launch_bounds__(256) void k_prep(
    const int* __restrict__ mask, ull* __restrict__ pm,
    const void* x, const void* Wq, const void* bq, const void* Wk, const void* bk,
    const void* Wv, const void* bv, const void* ln1w, const void* ln1b,
    float* x1f, bf16* Qp, bf16* Kp, bf16* Vti,
    const void* Wo, const void* W1, const void* W2,
    bf16* WoT, bf16* W1T, bf16* W2T)
{
  __shared__ float xs[4][64];
  const int w = threadIdx.x >> 6, lane = threadIdx.x & 63;
  if (blockIdx.x < 2048){
    const int row = blockIdx.x * 4 + w;               // 0..8191 (= b*2048+q)
    const int b = row >> 11, q = row & 2047;
    const int* rp = mask + (size_t)row * SEQ;
    ull* op = pm + ((size_t)(b * 128 + (q >> 4))) * 512 + (q & 15) * 2;
#pragma unroll
    for (int it = 0; it < 8; ++it){
      const int c0 = it * 256 + lane;
      ull m0 = __ballot(rp[c0] == 1);
      ull m1 = __ballot(rp[c0 + 64] == 1);
      ull m2 = __ballot(rp[c0 + 128] == 1);
      ull m3 = __ballot(rp[c0 + 192] == 1);
      if (lane == 0){
#pragma unroll
        for (int j = 0; j < 4; ++j){
          const int wi = it * 4 + j;
          const ull mv = (j == 0) ? m0 : (j == 1) ? m1 : (j == 2) ? m2 : m3;
          op[(wi >> 1) * 32 + (wi & 1)] = mv;
        }
      }
    }
    return;
  }
  if (blockIdx.x >= 4240){
    // ones-rows of Vti: [bh][tt][8][j] = 1.0  (65536 bf16)
    const int idx = (blockIdx.x - 4240) * 256 + threadIdx.x;
    const int bh = idx >> 11;
    const int rem = idx & 2047;
    const int tt = rem >> 4, j = rem & 15;
    Vti[(((size_t)(bh * 128 + tt)) * 9 + 8) * 16 + j] = __float2bfloat16(1.0f);
    return;
  }
  if (blockIdx.x >= 4096){
    if (detect_f32(x)) wt_body<1>(Wo, W1, W2, WoT, W1T, W2T);
    else               wt_body<0>(Wo, W1, W2, WoT, W1T, W2T);
    return;
  }
  if (detect_f32(x))
    ln_qkv_body<1>(x, Wq, bq, Wk, bk, Wv, bv, ln1w, ln1b, x1f, Qp, Kp, Vti, xs);
  else
    ln_qkv_body<0>(x, Wq, bq, Wk, bk, Wv, bv, ln1w, ln1b, x1f, Qp, Kp, Vti, xs);
}

// ---------------- Kernel B: flash attention, 2 q-tiles/wave + K/4-split --------
// 256 thr = 4 waves = 1 head x 4 K-quarters; 32 queries/block. Fixed-ref
// softmax (raw v_exp); denominator via V ones-row; quarters merged additively
// through LDS. Mask decode is pure 32-bit. NO scheduling intrinsics in the
// main loop: sched_barrier (r20) AND setprio (r22) both form scheduler-region
// boundaries that keep both prefetch buffers live -> partial spill (WRITE
// 1->6.5MB) that costs more than they gain. No inline asm (r8/r9/r11).
#define LOADT(PB, T) do {                                                          \
    const int tt_ = (T);                                                           \
    _Pragma("unroll")                                                              \
    for (int i_ = 0; i_ < 8; ++i_){                                                \
      kf[PB][i_] = *reinterpret_cast<const s4v*>(kb8 + (size_t)(tt_ * 128 + i_ * 16) * 8); \
      vf[PB][i_] = *reinterpret_cast<const s4v*>(vb8 + (size_t)(tt_ * 8 + i_) * 144);      \
    }                                                                              \
    mwvA[PB] = pbA[tt_ * 16];                                                      \
    mwvB[PB] = pbB[tt_ * 16];                                                      \
  } while (0)

#define QTILE(PB, C, WLO, WHI, QF, ACCA, ACCB) do {                                \
    f32x4 st_[4];                                                                  \
    _Pragma("unroll")                                                              \
    for (int i_ = 0; i_ < 4; ++i_)                                                 \
      st_[i_] = __builtin_amdgcn_mfma_f32_16x16x16bf16_1k(kf[PB][(C) * 4 + i_], QF, zf, 0, 0, 0); \
    _Pragma("unroll")                                                              \
    for (int i_ = 0; i_ < 4; ++i_){                                                \
      const unsigned w32_ = (i_ < 2) ? (WLO) : (WHI);                              \
      const unsigned b4_ = (w32_ >> (16 * (i_ & 1) + sh4)) & 0xFu;                 \
      float p0_ = (b4_ & 1u) ? 0.f : EXP2(st_[i_][0]);                             \
      float p1_ = (b4_ & 2u) ? 0.f : EXP2(st_[i_][1]);                             \
      float p2_ = (b4_ & 4u) ? 0.f : EXP2(st_[i_][2]);                             \
      float p3_ = (b4_ & 8u) ? 0.f : EXP2(st_[i_][3]);                             \
      union { unsigned u[2]; s4v s; } pu_;                                         \
      pu_.u[0] = bfs2(p0_, p1_);                                                   \
      pu_.u[1] = bfs2(p2_, p3_);                                                   \
      if (i_ & 1) ACCB = __builtin_amdgcn_mfma_f32_16x16x16bf16_1k(vf[PB][(C) * 4 + i_], pu_.s, ACCB, 0, 0, 0); \
      else        ACCA = __builtin_amdgcn_mfma_f32_16x16x16bf16_1k(vf[PB][(C) * 4 + i_], pu_.s, ACCA, 0, 0, 0); \
    }                                                                              \
  } while (0)

#define COMPT(PB) do {                                                             \
    QTILE(PB, 0, mwvA[PB].x, mwvA[PB].y, qfA, accA0, accB0);                       \
    QTILE(PB, 0, mwvB[PB].x, mwvB[PB].y, qfB, accA1, accB1);                       \
    QTILE(PB, 1, mwvA[PB].z, mwvA[PB].w, qfA, accA0, accB0);                       \
    QTILE(PB, 1, mwvB[PB].z, mwvB[PB].w, qfB, accA1, accB1);                       \
  } while (0)

__global__ __launch_bounds__(256, 4) void k_attn(
    const bf16* __restrict__ Qp, const bf16* __restrict__ Kp,
    const bf16* __restrict__ Vti, const uint4* __restrict__ pmi,
    bf16* __restrict__ ctxb)
{
  const int blk = blockIdx.x;                 // 2048 = b(4) x qt(64) x h(8)
  const int h  = blk & 7;
  const int qt = (blk >> 3) & 63;
  const int b  = blk >> 9;
  const int kq = threadIdx.x >> 6;            // K-quarter 0..3
  const int bh = b * 8 + h;
  const int q0 = qt * 32;
  const int lane = threadIdx.x & 63;
  const int g = lane >> 4, qi = lane & 15;
  const int sh4 = 4 * g;
  const int tbase = kq * 4;                   // 4 tiles of 128 keys per wave

  __shared__ float mlds[3][2][16][17];

  s4v qfA = {0, 0, 0, 0}, qfB = {0, 0, 0, 0};
  if (g < 2){
    qfA = *reinterpret_cast<const s4v*>(Qp + ((size_t)(bh * SEQ + q0 + qi)) * 8 + sh4);
    qfB = *reinterpret_cast<const s4v*>(Qp + ((size_t)(bh * SEQ + q0 + 16 + qi)) * 8 + sh4);
  }

  const bf16*  kb8 = Kp + ((size_t)bh * SEQ + qi) * 8 + sh4;
  const bf16*  vb8 = Vti + (size_t)bh * 128 * 144 + qi * 16 + sh4;
  const uint4* pbA = pmi + (size_t)(b * 128 + 2 * qt) * 256 + qi;
  const uint4* pbB = pbA + 256;

  f32x4 accA0 = {0.f, 0.f, 0.f, 0.f}, accB0 = {0.f, 0.f, 0.f, 0.f};
  f32x4 accA1 = {0.f, 0.f, 0.f, 0.f}, accB1 = {0.f, 0.f, 0.f, 0.f};
  const f32x4 zf = {0.f, 0.f, 0.f, 0.f};

  s4v kf[2][8], vf[2][8];
  uint4 mwvA[2], mwvB[2];

  LOADT(0, tbase);
#pragma unroll
  for (int it2 = 0; it2 < 2; ++it2){
    LOADT(1, tbase + ((2 * it2 + 1) & 3));
    COMPT(0);
    LOADT(0, tbase + ((2 * it2 + 2) & 3));
    COMPT(1);
  }

  f32x4 acc0, acc1;
#pragma unroll
  for (int r = 0; r < 4; ++r){
    acc0[r] = accA0[r] + accB0[r];
    acc1[r] = accA1[r] + accB1[r];
  }

  // merge the four K-quarters (additive: fixed-ref softmax, unnormalized)
  if (kq > 0){
#pragma unroll
    for (int r = 0; r < 4; ++r){
      mlds[kq - 1][0][4 * g + r][qi] = acc0[r];
      mlds[kq - 1][1][4 * g + r][qi] = acc1[r];
    }
  }
  __syncthreads();
  if (kq == 0){
#pragma unroll
    for (int j = 0; j < 3; ++j)
#pragma unroll
      for (int r = 0; r < 4; ++r){
        acc0[r] += mlds[j][0][4 * g + r][qi];
        acc1[r] += mlds[j][1][4 * g + r][qi];
      }
    // denominator lives in D row 8 (lane 32+qi, reg 0), col = query
    const float s0 = __shfl(acc0[0], 32 + qi, 64);
    const float s1 = __shfl(acc1[0], 32 + qi, 64);
    if (g < 2){
      const float i0 = 1.f / s0, i1 = 1.f / s1;
      s4v oA, oB;
#pragma unroll
      for (int r = 0; r < 4; ++r){ oA[r] = bfs(acc0[r] * i0); oB[r] = bfs(acc1[r] * i1); }
      *reinterpret_cast<s4v*>(ctxb + ((size_t)(bh * SEQ + q0 + qi)) * 8 + sh4) = oA;
      *reinterpret_cast<s4v*>(ctxb + ((size_t)(bh * SEQ + q0 + 16 + qi)) * 8 + sh4) = oB;
    }
  }
}

// ---------------- Kernel C: MFMA FFN, u-split across 4 waves -------------------
template<int F32>
__device__ __forceinline__ void ffn_mfma_body(
    const bf16* __restrict__ ctxb, const float* __restrict__ x1f,
    const bf16* __restrict__ WoT, const bf16* __restrict__ W1T, const bf16* __restrict__ W2T,
    const void* bo, const void* b1, const void* b2,
    const void* ln2w, const void* ln2b, void* out, float (*mlds)[16][64])
{
  const int lane = threadIdx.x & 63;
  const int uq = threadIdx.x >> 6;    // u-quarter 0..3
  const int row0 = blockIdx.x * 16;
  const int xr = lane & 15;           // x-row within tile == D col
  const int ko = (lane >> 4) * 4;     // k/col offset of this lane's quad
  const f32x4 zf = {0.f, 0.f, 0.f, 0.f};

  // ctx B-frags (K-steps kk=0..3):  B[k=16kk+ko+j][n=xr]
  s4v cb[4];
#pragma unroll
  for (int kk = 0; kk < 4; ++kk)
    cb[kk] = *reinterpret_cast<const s4v*>(ctxb + (size_t)(row0 + xr) * 64 + kk * 16 + ko);

  // GEMM1: proj^T tiles; x2 = 2*x1 + proj + bo   (lane holds x2[xr][16t+ko+r])
  float x2v[4][4];
#pragma unroll
  for (int t = 0; t < 4; ++t){
    f32x4 acc = zf;
#pragma unroll
    for (int kk = 0; kk < 4; ++kk){
      s4v a = *reinterpret_cast<const s4v*>(WoT + (size_t)(t * 16 + xr) * 64 + kk * 16 + ko);
      acc = __builtin_amdgcn_mfma_f32_16x16x16bf16_1k(a, cb[kk], acc, 0, 0, 0);
    }
    float4 x1q = *reinterpret_cast<const float4*>(x1f + (size_t)(row0 + xr) * 64 + t * 16 + ko);
#pragma unroll
    for (int r = 0; r < 4; ++r)
      x2v[t][r] = 2.f * (&x1q.x)[r] + acc[r] + ldf<F32>(bo, t * 16 + ko + r);
  }

  // LN2: all 16 values belong to row xr; row spans lanes {xr, xr+16, xr+32, xr+48}
  float s = 0.f;
#pragma unroll
  for (int t = 0; t < 4; ++t)
#pragma unroll
    for (int r = 0; r < 4; ++r) s += x2v[t][r];
  s += __shfl_xor(s, 16, 64);
  s += __shfl_xor(s, 32, 64);
  const float mu = s * 0.015625f;
  float vs = 0.f;
#pragma unroll
  for (int t = 0; t < 4; ++t)
#pragma unroll
    for (int r = 0; r < 4; ++r){ float d = x2v[t][r] - mu; vs += d * d; }
  vs += __shfl_xor(vs, 16, 64);
  vs += __shfl_xor(vs, 32, 64);
  const float rs = rsqrtf(vs * 0.015625f + 1e-5f);

  // x3 frags: B-operand for GEMM2, K-step t  (j == r)
  s4v xb[4];
#pragma unroll
  for (int t = 0; t < 4; ++t)
#pragma unroll
    for (int r = 0; r < 4; ++r)
      xb[t][r] = bfs((x2v[t][r] - mu) * rs * ldf<F32>(ln2w, t * 16 + ko + r)
                     + ldf<F32>(ln2b, t * 16 + ko + r));

  // GEMM2 + b1 + exact gelu for this wave's 4 u-tiles
  s4v gb[4];
#pragma unroll
  for (int uu = 0; uu < 4; ++uu){
    const int u = uq * 4 + uu;
    f32x4 acc = zf;
#pragma unroll
    for (int t = 0; t < 4; ++t){
      s4v a = *reinterpret_cast<const s4v*>(W1T + (size_t)(u * 16 + xr) * 64 + t * 16 + ko);
      acc = __builtin_amdgcn_mfma_f32_16x16x16bf16_1k(a, xb[t], acc, 0, 0, 0);
    }
#pragma unroll
    for (int r = 0; r < 4; ++r){
      float h1 = acc[r] + ldf<F32>(b1, u * 16 + ko + r);
      gb[uu][r] = bfs(0.5f * h1 * (1.f + erff(h1 * 0.70710678f)));
    }
  }

  // partial GEMM3 over this wave's u-tiles
  f32x4 oacc[4];
#pragma unroll
  for (int t = 0; t < 4; ++t){
    f32x4 acc = zf;
#pragma unroll
    for (int uu = 0; uu < 4; ++uu){
      const int u = uq * 4 + uu;
      s4v a = *reinterpret_cast<const s4v*>(W2T + (size_t)(t * 16 + xr) * 256 + u * 16 + ko);
      acc = __builtin_amdgcn_mfma_f32_16x16x16bf16_1k(a, gb[uu], acc, 0, 0, 0);
    }
    oacc[t] = acc;
  }

  // merge partials (additive) through LDS; wave 0 finalizes
  if (uq > 0){
#pragma unroll
    for (int t = 0; t < 4; ++t)
#pragma unroll
      for (int r = 0; r < 4; ++r)
        mlds[uq - 1][xr][t * 16 + ko + r] = oacc[t][r];
  }
  __syncthreads();
  if (uq == 0){
#pragma unroll
    for (int t = 0; t < 4; ++t){
#pragma unroll
      for (int j = 0; j < 3; ++j)
#pragma unroll
        for (int r = 0; r < 4; ++r)
          oacc[t][r] += mlds[j][xr][t * 16 + ko + r];
      const size_t oidx = (size_t)(row0 + xr) * 64 + t * 16 + ko;
      if constexpr (F32){
        float4 o;
#pragma unroll
        for (int r = 0; r < 4; ++r)
          (&o.x)[r] = x2v[t][r] + oacc[t][r] + ldf<F32>(b2, t * 16 + ko + r);
        *reinterpret_cast<float4*>((float*)out + oidx) = o;
      } else {
        s4v o;
#pragma unroll
        for (int r = 0; r < 4; ++r)
          o[r] = bfs(x2v[t][r] + oacc[t][r] + ldf<F32>(b2, t * 16 + ko + r));
        *reinterpret_cast<s4v*>((bf16*)out + oidx) = o;
      }
    }
  }
}

__global__ __launch_bounds__(256) void k_ffn(
    const void* xprobe,
    const bf16* __restrict__ ctxb, const float* __restrict__ x1f,
    const bf16* __restrict__ WoT, const bf16* __restrict__ W1T, const bf16* __restrict__ W2T,
    const void* bo, const void* b1, const void* b2,
    const void* ln2w, const void* ln2b, void* out)
{
  __shared__ float mlds[3][16][64];
  if (detect_f32(xprobe))
    ffn_mfma_body<1>(ctxb, x1f, WoT, W1T, W2T, bo, b1, b2, ln2w, ln2b, out, mlds);
  else
    ffn_mfma_body<0>(ctxb, x1f, WoT, W1T, W2T, bo, b1, b2, ln2w, ln2b, out, mlds);
}

extern "C" void kernel_launch(void* const* d_in, const int* in_sizes, int n_in,
                              void* d_out, int out_size, void* d_ws, size_t ws_size,
                              hipStream_t stream)
{
  (void)in_sizes; (void)n_in; (void)out_size; (void)ws_size;
  const void* x    = d_in[0];
  const int*  mask = (const int*)d_in[1];
  const void* Wq = d_in[2];
  const void* bq = d_in[3];
  const void* Wk = d_in[4];
  const void* bk = d_in[5];
  const void* Wv = d_in[6];
  const void* bv = d_in[7];
  const void* Wo = d_in[8];
  const void* bo = d_in[9];
  const void* W1 = d_in[10];
  const void* b1 = d_in[11];
  const void* W2 = d_in[12];
  const void* b2 = d_in[13];
  const void* ln1w = d_in[14];
  const void* ln1b = d_in[15];
  const void* ln2w = d_in[16];
  const void* ln2b = d_in[17];

  char* ws = (char*)d_ws;
  float* x1f = (float*)(ws + 0);               // 2 MB     [B][S][64] f32
  bf16*  Qp  = (bf16*)(ws + (2u << 20));       // 1 MB     [bh][s][8] bf16 (pre-scaled)
  bf16*  Kp  = (bf16*)(ws + (3u << 20));       // 1 MB     [bh][s][8]
  bf16*  Vti = (bf16*)(ws + (5u << 20));       // 1.125 MB [bh][tt][9][16], row8=ones
  bf16*  ctxb= (bf16*)(ws + (25u << 18));      // 1 MB     [B][H][S][8] bf16 (@6.25MB)
  bf16*  WoT = (bf16*)(ws + (29u << 18));      // 8 KB     [64][64]  (@7.25MB)
  bf16*  W1T = (bf16*)(ws + (29u << 18) + 8192);   // 32 KB [256][64]
  bf16*  W2T = (bf16*)(ws + (29u << 18) + 40960);  // 32 KB [64][256]
  ull*   pm  = (ull*)(ws + (33u << 18));       // 2 MB     packed mask (@8.25MB)

  k_prep<<<4496, 256, 0, stream>>>(mask, pm, x, Wq, bq, Wk, bk, Wv, bv, ln1w, ln1b,
                                   x1f, Qp, Kp, Vti, Wo, W1, W2, WoT, W1T, W2T);
  k_attn<<<2048, 256, 0, stream>>>(Qp, Kp, Vti, (const uint4*)pm, ctxb);
  k_ffn<<<512, 256, 0, stream>>>(x, ctxb, x1f, WoT, W1T, W2T, bo, b1, b2, ln2w, ln2b, d_out);
}